// Round 1
// baseline (89.366 us; speedup 1.0000x reference)
//
#include <hip/hip_runtime.h>

#define TT 14
#define LL 26
#define EE 128
#define NB 16384
#define BPB 8              // batches per block
#define ROWS (BPB * TT)    // 112 (b,t) rows per block

// ---------------------------------------------------------------------------
// Setup: fold conv into an effective emission matrix.
//   Weff[e][l] = sum_{ky,kx} conv_w[ky][kx] * Wmat[l][oy*8+ox],
//                oy = iy-ky+2, ox = ix-kx+2 (SAME padding, cross-correlation)
//   be[l]      = conv_b * sum_e Wmat[l][e]
// ---------------------------------------------------------------------------
__global__ __launch_bounds__(256) void crf_setup(
    const float* __restrict__ conv_w, const float* __restrict__ conv_b,
    const float* __restrict__ params, float* __restrict__ weff,
    float* __restrict__ be) {
  int idx = blockIdx.x * 256 + threadIdx.x;
  if (idx < EE * LL) {
    int e = idx / LL, l = idx - e * LL;
    int iy = e >> 3, ix = e & 7;
    float s = 0.f;
    for (int ky = 0; ky < 5; ++ky) {
      int oy = iy - ky + 2;
      if (oy < 0 || oy >= 16) continue;
      for (int kx = 0; kx < 5; ++kx) {
        int ox = ix - kx + 2;
        if (ox < 0 || ox >= 8) continue;
        s += conv_w[ky * 5 + kx] * params[l * EE + oy * 8 + ox];
      }
    }
    weff[e * LL + l] = s;  // layout [e][l] so main kernel reads are uniform
  }
  if (idx < LL) {
    float s = 0.f;
    for (int e = 0; e < EE; ++e) s += params[idx * EE + e];
    be[idx] = conv_b[0] * s;
  }
}

// ---------------------------------------------------------------------------
// Fused emission GEMM + Viterbi + backtrack. One block = 8 batches.
// ---------------------------------------------------------------------------
__global__ __launch_bounds__(128) void crf_main(
    const float* __restrict__ X, const float* __restrict__ params,
    const float* __restrict__ weff, const float* __restrict__ be,
    float* __restrict__ out) {
  __shared__ float emis_s[ROWS][28];           // padded (28) for bank spread
  __shared__ float Ts[LL * LL];                // Trans[i][j]
  __shared__ unsigned char bp_s[BPB][TT - 1][28];

  const int tid = threadIdx.x;
  const int b0 = blockIdx.x * BPB;

  for (int i = tid; i < LL * LL; i += 128) Ts[i] = params[LL * EE + i];

  // ---- Phase 1: emissions. Thread tid owns row (b0*14 + tid), tid < 112.
  if (tid < ROWS) {
    const float4* xv =
        reinterpret_cast<const float4*>(X) + (size_t)(b0 * TT + tid) * 32;
    float acc[LL];
#pragma unroll
    for (int l = 0; l < LL; ++l) acc[l] = 0.f;
    for (int e4 = 0; e4 < 32; ++e4) {
      float4 v = xv[e4];
      const float* w = weff + e4 * 4 * LL;  // wave-uniform address -> s_load
#pragma unroll
      for (int l = 0; l < LL; ++l)
        acc[l] += v.x * w[l] + v.y * w[LL + l] + v.z * w[2 * LL + l] +
                  v.w * w[3 * LL + l];
    }
#pragma unroll
    for (int l = 0; l < LL; ++l) emis_s[tid][l] = acc[l] + be[l];
  }
  __syncthreads();

  // ---- Phase 2: Viterbi. Each 32-lane half-wave owns one batch, lane j = label.
  const int lane = tid & 63;
  const int wv = tid >> 6;        // wave id 0..1
  const int j = lane & 31;        // label lane
  const int hb = lane >> 5;       // half selector
  const int jj = (j < LL) ? j : (LL - 1);  // clamped for safe loads

  for (int p = 0; p < 2; ++p) {
    const int bl = p * 4 + wv * 2 + hb;  // 0..7
    float Tcol[LL];
#pragma unroll
    for (int i = 0; i < LL; ++i) Tcol[i] = Ts[i * LL + jj];  // Trans[i][j]

    float alpha = emis_s[bl * TT + 0][jj];
    for (int t = 1; t < TT; ++t) {
      float m = -__builtin_inff();
      int bp = 0;
#pragma unroll
      for (int i = 0; i < LL; ++i) {
        float a_i = __shfl(alpha, i, 32);  // broadcast from own half
        float s = a_i + Tcol[i];
        if (s > m) { m = s; bp = i; }      // strict > : first-index tie-break
      }
      alpha = m + emis_s[bl * TT + t][jj];
      if (j < LL) bp_s[bl][t - 1][j] = (unsigned char)bp;
    }

    // argmax over labels (max value, lowest index on tie = first occurrence)
    float val = (j < LL) ? alpha : -__builtin_inff();
    int idx = j;
#pragma unroll
    for (int off = 16; off >= 1; off >>= 1) {
      float v2 = __shfl_xor(val, off, 32);
      int i2 = __shfl_xor(idx, off, 32);
      if (v2 > val || (v2 == val && i2 < idx)) { val = v2; idx = i2; }
    }

    __syncthreads();  // make bp_s writes visible before backtrack

    if (j == 0) {
      const int b = b0 + bl;
      out[NB * TT + b] = val;  // score
      int lbl = idx;
      for (int t = TT - 1; t >= 1; --t) {
        out[b * TT + t] = (float)lbl;
        lbl = bp_s[bl][t - 1][lbl];
      }
      out[b * TT + 0] = (float)lbl;
    }
    __syncthreads();
  }
}

extern "C" void kernel_launch(void* const* d_in, const int* in_sizes, int n_in,
                              void* d_out, int out_size, void* d_ws,
                              size_t ws_size, hipStream_t stream) {
  const float* X = (const float*)d_in[0];
  const float* conv_w = (const float*)d_in[1];
  const float* conv_b = (const float*)d_in[2];
  const float* params = (const float*)d_in[3];
  float* out = (float*)d_out;
  float* weff = (float*)d_ws;           // 3328 floats
  float* be = weff + EE * LL;           // 26 floats

  hipLaunchKernelGGL(crf_setup, dim3(13), dim3(256), 0, stream, conv_w, conv_b,
                     params, weff, be);
  hipLaunchKernelGGL(crf_main, dim3(NB / BPB), dim3(128), 0, stream, X, params,
                     weff, be, out);
}